// Round 6
// baseline (113.136 us; speedup 1.0000x reference)
//
#include <hip/hip_runtime.h>

#define B_ 8
#define T_ 256
#define U_ 64
#define U1_ 65
#define V_ 512
#define NDIAGP_ 336   // padded diagonal count (stage over-read stays in-bounds)
#define NT_ 4         // t-rows per k_logprobs block
#define CH_ 64        // diagonals per k_alpha chunk
#define NCH_ 5        // chunks cover d = 1..320 (d=320 self-gated)
#define LBUF_ 4352    // floats per LDS buffer (17 * 256, covers 65-row chunk + pad)

#define LOG2E_ 1.4426950408889634f
#define LN2_   0.6931471805599453f

// ---------------------------------------------------------------------------
// Kernel 0: edec = exp(dec), elementwise (B*U1*V floats, float4)
// ---------------------------------------------------------------------------
__global__ __launch_bounds__(256) void k_exp(const float* __restrict__ x,
                                             float* __restrict__ y, int n4)
{
    int i = blockIdx.x * blockDim.x + threadIdx.x;
    if (i < n4) {
        float4 v = ((const float4*)x)[i];
        float4 r;
        r.x = __expf(v.x); r.y = __expf(v.y);
        r.z = __expf(v.z); r.w = __expf(v.w);
        ((float4*)y)[i] = r;
    }
}

// ---------------------------------------------------------------------------
// Kernel 1: block = (b, group of 4 t's). lse2[u] = log2( exp(enc_row) . edec_row[u] ).
// Writes diagonal-major log2-domain:
//   BLD[b][t+u][u] = (enc[0]+dec[u][0])*log2e     - lse2
//   EMD[b][t+u][u] = (enc[tgt]+dec[u][tgt])*log2e - lse2
// ---------------------------------------------------------------------------
__global__ __launch_bounds__(256) void k_logprobs(
    const float* __restrict__ enc, const float* __restrict__ dec,
    const float* __restrict__ edec, const int* __restrict__ targets,
    float* __restrict__ BLD, float* __restrict__ EMD)
{
    const int blk  = blockIdx.x;           // 0 .. B_*T_/NT_ - 1
    const int b    = blk % B_;
    const int tg   = blk / B_;
    const int t0   = tg * NT_;
    const int wave = threadIdx.x >> 6;
    const int lane = threadIdx.x & 63;

    float4 xe0[NT_], xe1[NT_];
    #pragma unroll
    for (int j = 0; j < NT_; ++j) {
        const float* erow = enc + (size_t)(b * T_ + t0 + j) * V_;
        float4 e0 = *(const float4*)(erow + lane * 4);
        float4 e1 = *(const float4*)(erow + 256 + lane * 4);
        xe0[j].x = __expf(e0.x); xe0[j].y = __expf(e0.y);
        xe0[j].z = __expf(e0.z); xe0[j].w = __expf(e0.w);
        xe1[j].x = __expf(e1.x); xe1[j].y = __expf(e1.y);
        xe1[j].z = __expf(e1.z); xe1[j].w = __expf(e1.w);
    }

    for (int u = wave; u <= U_; u += 4) {
        const float* xdrow = edec + (size_t)(b * U1_ + u) * V_;
        float4 d0 = *(const float4*)(xdrow + lane * 4);
        float4 d1 = *(const float4*)(xdrow + 256 + lane * 4);

        float s[NT_];
        #pragma unroll
        for (int j = 0; j < NT_; ++j) {
            float sA = xe0[j].x * d0.x;
            float sB = xe1[j].x * d1.x;
            sA = fmaf(xe0[j].y, d0.y, sA);  sB = fmaf(xe1[j].y, d1.y, sB);
            sA = fmaf(xe0[j].z, d0.z, sA);  sB = fmaf(xe1[j].z, d1.z, sB);
            sA = fmaf(xe0[j].w, d0.w, sA);  sB = fmaf(xe1[j].w, d1.w, sB);
            s[j] = sA + sB;
        }

        #pragma unroll
        for (int off = 32; off > 0; off >>= 1) {
            #pragma unroll
            for (int j = 0; j < NT_; ++j)
                s[j] += __shfl_xor(s[j], off, 64);
        }

        if (lane == 0) {
            const float* dr = dec + (size_t)(b * U1_ + u) * V_;
            const float d_blank = dr[0];
            int   tgt = 0;
            float d_tgt = 0.0f;
            if (u < U_) { tgt = targets[b * U_ + u]; d_tgt = dr[tgt]; }
            #pragma unroll
            for (int j = 0; j < NT_; ++j) {
                const int t  = t0 + j;
                const int dg = t + u;
                const float lse2 = log2f(s[j]);
                const float* er = enc + (size_t)(b * T_ + t) * V_;
                BLD[((size_t)b * NDIAGP_ + dg) * U1_ + u] =
                    (er[0] + d_blank) * LOG2E_ - lse2;
                if (u < U_)
                    EMD[((size_t)b * NDIAGP_ + dg) * U_ + u] =
                        (er[tgt] + d_tgt) * LOG2E_ - lse2;
            }
        }
    }
}

// ---------------------------------------------------------------------------
// Kernel 2: alpha wavefront recursion (log2 domain), one block (4 waves) per
// batch. Chunks of 64 diagonals double-buffered in LDS: all waves stage chunk
// c+1 via global_load_lds while wave 0 computes chunk c from LDS.
// ---------------------------------------------------------------------------
__device__ __forceinline__ float lae2(float x, float y) {
    float m = fmaxf(x, y);
    return m + log2f(1.0f + exp2f(-fabsf(x - y)));
}

// stage chunk c_: BL/EM diag rows [64c, 64c+66.x) into buffer (c_&1).
// 17 instructions x 1 KiB each per array; chunk byte offsets are 16B-aligned.
#define STAGE(c_) do {                                                          \
    const float* gbl = BLb + (size_t)(c_) * CH_ * U1_;                          \
    const float* gem = EMb + (size_t)(c_) * CH_ * U_;                           \
    float* lbl_ = sBL[(c_) & 1];                                                \
    float* lem_ = sEM[(c_) & 1];                                                \
    for (int i = wave; i < 17; i += 4) {                                        \
        __builtin_amdgcn_global_load_lds(                                       \
            (const __attribute__((address_space(1))) void*)(gbl + i * 256 + lane * 4), \
            (__attribute__((address_space(3))) void*)(lbl_ + i * 256), 16, 0, 0);      \
        __builtin_amdgcn_global_load_lds(                                       \
            (const __attribute__((address_space(1))) void*)(gem + i * 256 + lane * 4), \
            (__attribute__((address_space(3))) void*)(lem_ + i * 256), 16, 0, 0);      \
    }                                                                           \
} while (0)

// relative row s = (d-1) - d0 = 8g + j  (recursion at diag d reads diag d-1)
#define LOADL(PB, PE, PX, g_) do {                                              \
    _Pragma("unroll")                                                           \
    for (int j = 0; j < 8; ++j) {                                               \
        const int s = 8 * (g_) + j;                                             \
        PB[j] = lbl[s * U1_ + lane];                                            \
        PE[j] = lem[s * U_ + lane];                                             \
        PX[j] = lbl[s * U1_ + 64];                                              \
    }                                                                           \
} while (0)

#define COMPL(PB, PE, PX, g_) do {                                              \
    _Pragma("unroll")                                                           \
    for (int j = 0; j < 8; ++j) {                                               \
        const int d = d0 + 8 * (g_) + 1 + j;                                    \
        float em    = __shfl_up(PE[j], 1, 64);                                  \
        float aleft = __shfl_up(a, 1, 64);                                      \
        float aold  = a;                                                        \
        const int t = d - lane;                                                 \
        if (t >= 0 && t < T_) {                                                 \
            float na;                                                           \
            if (t == 0)          na = aleft + em;                               \
            else if (lane == 0)  na = a + PB[j];                                \
            else                 na = lae2(a + PB[j], aleft + em);              \
            a = na;                                                             \
            if (t == il - 1 && lane == tl)                                      \
                atomicAdd(out, -(a + BLb[(size_t)(il - 1 + tl) * U1_ + tl]) * (LN2_ / B_)); \
        }                                                                       \
        if (lane == 63) {                                                       \
            const int t2 = d - 64;                                              \
            if (t2 >= 0 && t2 < T_) {                                           \
                float y2 = aold + PE[j];                                        \
                a2 = (t2 == 0) ? y2 : lae2(a2 + PX[j], y2);                     \
                if (t2 == il - 1 && 64 == tl)                                   \
                    atomicAdd(out, -(a2 + BLb[(size_t)(il - 1 + tl) * U1_ + tl]) * (LN2_ / B_)); \
            }                                                                   \
        }                                                                       \
    }                                                                           \
} while (0)

__global__ __launch_bounds__(256) void k_alpha(
    const float* __restrict__ BLD, const float* __restrict__ EMD,
    const int* __restrict__ il_, const int* __restrict__ tl_,
    float* __restrict__ out)
{
    __shared__ __align__(16) float sBL[2][LBUF_];
    __shared__ __align__(16) float sEM[2][LBUF_];

    const int b    = blockIdx.x;
    const int wave = threadIdx.x >> 6;
    const int lane = threadIdx.x & 63;
    const int il   = il_[b];
    const int tl   = tl_[b];
    const float* BLb = BLD + (size_t)b * NDIAGP_ * U1_;
    const float* EMb = EMD + (size_t)b * NDIAGP_ * U_;

    float a  = 0.0f;   // alpha (log2) for u = lane
    float a2 = 0.0f;   // lane 63 only: u = 64

    if (il == 1 && tl == 0 && wave == 0 && lane == 0)
        atomicAdd(out, -(BLb[0]) * (LN2_ / B_));

    STAGE(0);
    __syncthreads();

    for (int c = 0; c < NCH_; ++c) {
        if (c + 1 < NCH_) STAGE(c + 1);

        if (wave == 0) {
            const float* lbl = sBL[c & 1];
            const float* lem = sEM[c & 1];
            const int d0 = CH_ * c;
            float pbA[8], peA[8], pxA[8];
            float pbB[8], peB[8], pxB[8];
            LOADL(pbA, peA, pxA, 0);
            for (int g = 0; g < 8; g += 2) {
                LOADL(pbB, peB, pxB, g + 1);
                COMPL(pbA, peA, pxA, g);
                if (g + 2 < 8) LOADL(pbA, peA, pxA, g + 2);
                COMPL(pbB, peB, pxB, g + 1);
            }
        }
        __syncthreads();   // publishes chunk c+1, drains this wave's loads
    }
}

extern "C" void kernel_launch(void* const* d_in, const int* in_sizes, int n_in,
                              void* d_out, int out_size, void* d_ws, size_t ws_size,
                              hipStream_t stream)
{
    const float* enc     = (const float*)d_in[0];
    const float* dec     = (const float*)d_in[1];
    const int*   targets = (const int*)d_in[2];
    const int*   il      = (const int*)d_in[3];
    const int*   tl      = (const int*)d_in[4];
    float*       out     = (float*)d_out;

    float* edec = (float*)d_ws;                           // B*U1*V
    float* BLD  = edec + (size_t)B_ * U1_ * V_;           // B*NDIAGP*U1
    float* EMD  = BLD  + (size_t)B_ * NDIAGP_ * U1_;      // B*NDIAGP*U

    (void)hipMemsetAsync(d_out, 0, sizeof(float), stream);

    const int n4 = B_ * U1_ * V_ / 4;
    k_exp<<<(n4 + 255) / 256, 256, 0, stream>>>(dec, edec, n4);
    k_logprobs<<<B_ * T_ / NT_, 256, 0, stream>>>(enc, dec, edec, targets, BLD, EMD);
    k_alpha<<<B_, 256, 0, stream>>>(BLD, EMD, il, tl, out);
}

// Round 7
// 84.822 us; speedup vs baseline: 1.3338x; 1.3338x over previous
//
#include <hip/hip_runtime.h>

#define B_ 8
#define T_ 256
#define U_ 64
#define U1_ 65
#define V_ 512
#define NDIAGP_ 336   // padded diagonal count (stage over-read stays in-bounds)
#define NT_ 4         // t-rows per k_logprobs block
#define CH_ 64        // diagonals per k_alpha chunk
#define NCH_ 5        // chunks cover d = 1..320 (d=320 self-gated)
#define LBUF_ 4352    // floats per LDS buffer (17 * 256 >= 64 rows * 65 cols)

#define LOG2E_ 1.4426950408889634f
#define LN2_   0.6931471805599453f
#define NEG_   -1.0e30f

// ---------------------------------------------------------------------------
// Kernel 0: edec = exp(dec), elementwise (B*U1*V floats, float4)
// ---------------------------------------------------------------------------
__global__ __launch_bounds__(256) void k_exp(const float* __restrict__ x,
                                             float* __restrict__ y, int n4)
{
    int i = blockIdx.x * blockDim.x + threadIdx.x;
    if (i < n4) {
        float4 v = ((const float4*)x)[i];
        float4 r;
        r.x = __expf(v.x); r.y = __expf(v.y);
        r.z = __expf(v.z); r.w = __expf(v.w);
        ((float4*)y)[i] = r;
    }
}

// ---------------------------------------------------------------------------
// Kernel 1: block = (b, group of 4 t's). lse2[u] = log2( exp(enc_row) . edec_row[u] ).
// Diagonal-major log2-domain outputs (both stride U1_=65):
//   BLD[b][t+u][u]   = (enc[0]+dec[u][0])*log2e     - lse2
//   EMD[b][t+u][u+1] = (enc[tgt]+dec[u][tgt])*log2e - lse2   (shifted +1 col!)
// The +1 shift lets k_alpha's lane u read emit[t][u-1] directly (no shuffle).
// ---------------------------------------------------------------------------
__global__ __launch_bounds__(256) void k_logprobs(
    const float* __restrict__ enc, const float* __restrict__ dec,
    const float* __restrict__ edec, const int* __restrict__ targets,
    float* __restrict__ BLD, float* __restrict__ EMD)
{
    const int blk  = blockIdx.x;           // 0 .. B_*T_/NT_ - 1
    const int b    = blk % B_;
    const int tg   = blk / B_;
    const int t0   = tg * NT_;
    const int wave = threadIdx.x >> 6;
    const int lane = threadIdx.x & 63;

    float4 xe0[NT_], xe1[NT_];
    #pragma unroll
    for (int j = 0; j < NT_; ++j) {
        const float* erow = enc + (size_t)(b * T_ + t0 + j) * V_;
        float4 e0 = *(const float4*)(erow + lane * 4);
        float4 e1 = *(const float4*)(erow + 256 + lane * 4);
        xe0[j].x = __expf(e0.x); xe0[j].y = __expf(e0.y);
        xe0[j].z = __expf(e0.z); xe0[j].w = __expf(e0.w);
        xe1[j].x = __expf(e1.x); xe1[j].y = __expf(e1.y);
        xe1[j].z = __expf(e1.z); xe1[j].w = __expf(e1.w);
    }

    for (int u = wave; u <= U_; u += 4) {
        const float* xdrow = edec + (size_t)(b * U1_ + u) * V_;
        float4 d0 = *(const float4*)(xdrow + lane * 4);
        float4 d1 = *(const float4*)(xdrow + 256 + lane * 4);

        float s[NT_];
        #pragma unroll
        for (int j = 0; j < NT_; ++j) {
            float sA = xe0[j].x * d0.x;
            float sB = xe1[j].x * d1.x;
            sA = fmaf(xe0[j].y, d0.y, sA);  sB = fmaf(xe1[j].y, d1.y, sB);
            sA = fmaf(xe0[j].z, d0.z, sA);  sB = fmaf(xe1[j].z, d1.z, sB);
            sA = fmaf(xe0[j].w, d0.w, sA);  sB = fmaf(xe1[j].w, d1.w, sB);
            s[j] = sA + sB;
        }

        #pragma unroll
        for (int off = 32; off > 0; off >>= 1) {
            #pragma unroll
            for (int j = 0; j < NT_; ++j)
                s[j] += __shfl_xor(s[j], off, 64);
        }

        if (lane == 0) {
            const float* dr = dec + (size_t)(b * U1_ + u) * V_;
            const float d_blank = dr[0];
            int   tgt = 0;
            float d_tgt = 0.0f;
            if (u < U_) { tgt = targets[b * U_ + u]; d_tgt = dr[tgt]; }
            #pragma unroll
            for (int j = 0; j < NT_; ++j) {
                const int t  = t0 + j;
                const int dg = t + u;
                const float lse2 = log2f(s[j]);
                const float* er = enc + (size_t)(b * T_ + t) * V_;
                BLD[((size_t)b * NDIAGP_ + dg) * U1_ + u] =
                    (er[0] + d_blank) * LOG2E_ - lse2;
                if (u < U_)
                    EMD[((size_t)b * NDIAGP_ + dg) * U1_ + (u + 1)] =
                        (er[tgt] + d_tgt) * LOG2E_ - lse2;
            }
        }
    }
}

// ---------------------------------------------------------------------------
// Kernel 2: alpha wavefront recursion (log2 domain), one block (4 waves) per
// batch. Waves 1-3 stage 64-diagonal chunks (double-buffered LDS,
// global_load_lds); wave 0 computes with a DPP wave_shr:1 lane shift on the
// serial chain (no LDS round trip) and branch-free cndmask patching.
// ---------------------------------------------------------------------------
__device__ __forceinline__ float wshr1(float x) {
    // DPP wave_shr:1 (0x138): lane i <- lane i-1, lane 0 <- 0 (bound_ctrl)
    return __int_as_float(__builtin_amdgcn_update_dpp(
        0, __float_as_int(x), 0x138, 0xf, 0xf, true));
}

#define STAGE(c_) do {                                                          \
    if (wave > 0) {                                                             \
        const float* gbl = BLb + (size_t)(c_) * CH_ * U1_;                      \
        const float* gem = EMb + (size_t)(c_) * CH_ * U1_;                      \
        float* lbl_ = sBL[(c_) & 1];                                            \
        float* lem_ = sEM[(c_) & 1];                                            \
        for (int i = wave - 1; i < 17; i += 3) {                                \
            __builtin_amdgcn_global_load_lds(                                   \
                (const __attribute__((address_space(1))) void*)(gbl + i * 256 + lane * 4), \
                (__attribute__((address_space(3))) void*)(lbl_ + i * 256), 16, 0, 0);      \
            __builtin_amdgcn_global_load_lds(                                   \
                (const __attribute__((address_space(1))) void*)(gem + i * 256 + lane * 4), \
                (__attribute__((address_space(3))) void*)(lem_ + i * 256), 16, 0, 0);      \
        }                                                                       \
    }                                                                           \
} while (0)

// relative row s = (d-1) - d0 = 8g + j  (recursion at diag d reads diag d-1)
#define LOADL(PB, PE, PX, PY, g_) do {                                          \
    _Pragma("unroll")                                                           \
    for (int j = 0; j < 8; ++j) {                                               \
        const int s = 8 * (g_) + j;                                             \
        PB[j] = lbl[s * U1_ + lane];                                            \
        PE[j] = lem[s * U1_ + lane];                                            \
        PX[j] = lbl[s * U1_ + 64];                                              \
        PY[j] = lem[s * U1_ + 64];                                              \
    }                                                                           \
} while (0)

#define COMPL(PB, PE, PX, PY, g_) do {                                          \
    _Pragma("unroll")                                                           \
    for (int j = 0; j < 8; ++j) {                                               \
        const int d = d0 + 8 * (g_) + 1 + j;                                    \
        float aleft = wshr1(a);                                                 \
        float aold  = a;                                                        \
        float x = a + PB[j];                                                    \
        float y = aleft + PE[j];                                                \
        if (d0 == 0) x = (lane == d) ? NEG_ : x;   /* t==0: no blank path */    \
        y = (lane == 0) ? NEG_ : y;                /* u==0: no emit path  */    \
        float m  = fmaxf(x, y);                                                 \
        float na = m + log2f(1.0f + exp2f(-fabsf(x - y)));                      \
        const int t = d - lane;                                                 \
        a = ((unsigned)t < (unsigned)T_) ? na : a;                              \
        const int t2 = d - 64;                     /* uniform */                \
        if (t2 >= 0 && t2 < T_) {                                               \
            float y2 = aold + PY[j];                                            \
            if (t2 == 0) a2 = y2;                                               \
            else {                                                              \
                float x2 = a2 + PX[j];                                          \
                float m2 = fmaxf(x2, y2);                                       \
                a2 = m2 + log2f(1.0f + exp2f(-fabsf(x2 - y2)));                 \
            }                                                                   \
        }                                                                       \
        if (d == dstar) {                          /* uniform, rare */          \
            float val = (tl == U_) ? a2 : a;                                    \
            if (lane == ((tl == U_) ? 63 : tl))                                 \
                atomicAdd(out, -(val + fblank) * (LN2_ / B_));                  \
        }                                                                       \
    }                                                                           \
} while (0)

__global__ __launch_bounds__(256) void k_alpha(
    const float* __restrict__ BLD, const float* __restrict__ EMD,
    const int* __restrict__ il_, const int* __restrict__ tl_,
    float* __restrict__ out)
{
    __shared__ __align__(16) float sBL[2][LBUF_];
    __shared__ __align__(16) float sEM[2][LBUF_];

    const int b    = blockIdx.x;
    const int wave = threadIdx.x >> 6;
    const int lane = threadIdx.x & 63;
    const int il   = il_[b];
    const int tl   = tl_[b];
    const int dstar = il - 1 + tl;
    const float* BLb = BLD + (size_t)b * NDIAGP_ * U1_;
    const float* EMb = EMD + (size_t)b * NDIAGP_ * U1_;
    const float fblank = BLb[(size_t)dstar * U1_ + tl];

    float a  = 0.0f;   // alpha (log2) for u = lane
    float a2 = 0.0f;   // u = 64 (lane 63's copy is the valid one)

    if (dstar == 0 && wave == 0 && lane == 0)
        atomicAdd(out, -fblank * (LN2_ / B_));

    STAGE(0);
    __syncthreads();

    for (int c = 0; c < NCH_; ++c) {
        if (c + 1 < NCH_) STAGE(c + 1);

        if (wave == 0) {
            const float* lbl = sBL[c & 1];
            const float* lem = sEM[c & 1];
            const int d0 = CH_ * c;
            float pbA[8], peA[8], pxA[8], pyA[8];
            float pbB[8], peB[8], pxB[8], pyB[8];
            LOADL(pbA, peA, pxA, pyA, 0);
            for (int g = 0; g < 8; g += 2) {
                LOADL(pbB, peB, pxB, pyB, g + 1);
                COMPL(pbA, peA, pxA, pyA, g);
                if (g + 2 < 8) LOADL(pbA, peA, pxA, pyA, g + 2);
                COMPL(pbB, peB, pxB, pyB, g + 1);
            }
        }
        __syncthreads();   // publishes chunk c+1, drains staging loads
    }
}

extern "C" void kernel_launch(void* const* d_in, const int* in_sizes, int n_in,
                              void* d_out, int out_size, void* d_ws, size_t ws_size,
                              hipStream_t stream)
{
    const float* enc     = (const float*)d_in[0];
    const float* dec     = (const float*)d_in[1];
    const int*   targets = (const int*)d_in[2];
    const int*   il      = (const int*)d_in[3];
    const int*   tl      = (const int*)d_in[4];
    float*       out     = (float*)d_out;

    float* edec = (float*)d_ws;                           // B*U1*V
    float* BLD  = edec + (size_t)B_ * U1_ * V_;           // B*NDIAGP*U1
    float* EMD  = BLD  + (size_t)B_ * NDIAGP_ * U1_;      // B*NDIAGP*U1

    (void)hipMemsetAsync(d_out, 0, sizeof(float), stream);

    const int n4 = B_ * U1_ * V_ / 4;
    k_exp<<<(n4 + 255) / 256, 256, 0, stream>>>(dec, edec, n4);
    k_logprobs<<<B_ * T_ / NT_, 256, 0, stream>>>(enc, dec, edec, targets, BLD, EMD);
    k_alpha<<<B_, 256, 0, stream>>>(BLD, EMD, il, tl, out);
}

// Round 8
// 66.380 us; speedup vs baseline: 1.7044x; 1.2778x over previous
//
#include <hip/hip_runtime.h>

#define B_ 8
#define T_ 256
#define U_ 64
#define U1_ 65
#define V_ 512
#define NDIAGP_ 336   // padded diagonal count (stage over-read stays in-bounds)
#define NT_ 4         // t-rows per k_logprobs block
#define CH_ 64        // diagonals per k_alpha chunk
#define NCH_ 5        // chunks cover d = 1..320 (d=320 self-gated)
#define LBBL_ 4352    // floats per BL LDS buffer (17*256 >= 64 rows * 65)
#define LBEM_ 4096    // floats per EM LDS buffer (16*256 = 64 rows * 64)

#define LOG2E_ 1.4426950408889634f
#define LN2_   0.6931471805599453f
#define NEG_   -1.0e30f

#if __has_builtin(__builtin_amdgcn_exp2f)
#define EXP2(x) __builtin_amdgcn_exp2f(x)
#else
#define EXP2(x) exp2f(x)
#endif
#if __has_builtin(__builtin_amdgcn_logf)
#define LOG2(x) __builtin_amdgcn_logf(x)
#else
#define LOG2(x) log2f(x)
#endif

// ---------------------------------------------------------------------------
// Kernel 0: edec = exp(dec), elementwise (B*U1*V floats, float4)
// ---------------------------------------------------------------------------
__global__ __launch_bounds__(256) void k_exp(const float* __restrict__ x,
                                             float* __restrict__ y, int n4)
{
    int i = blockIdx.x * blockDim.x + threadIdx.x;
    if (i < n4) {
        float4 v = ((const float4*)x)[i];
        float4 r;
        r.x = __expf(v.x); r.y = __expf(v.y);
        r.z = __expf(v.z); r.w = __expf(v.w);
        ((float4*)y)[i] = r;
    }
}

// ---------------------------------------------------------------------------
// Kernel 1: block = (b, group of 4 t's). lse2[u] = log2( exp(enc_row) . edec_row[u] ).
// Diagonal-major log2-domain outputs:
//   BLD[b][t+u][u]  (stride 65) = (enc[0]+dec[u][0])*log2e     - lse2
//   EMD[b][t+u][u]  (stride 64) = (enc[tgt]+dec[u][tgt])*log2e - lse2
// ---------------------------------------------------------------------------
__global__ __launch_bounds__(256) void k_logprobs(
    const float* __restrict__ enc, const float* __restrict__ dec,
    const float* __restrict__ edec, const int* __restrict__ targets,
    float* __restrict__ BLD, float* __restrict__ EMD)
{
    const int blk  = blockIdx.x;           // 0 .. B_*T_/NT_ - 1
    const int b    = blk % B_;
    const int tg   = blk / B_;
    const int t0   = tg * NT_;
    const int wave = threadIdx.x >> 6;
    const int lane = threadIdx.x & 63;

    float4 xe0[NT_], xe1[NT_];
    #pragma unroll
    for (int j = 0; j < NT_; ++j) {
        const float* erow = enc + (size_t)(b * T_ + t0 + j) * V_;
        float4 e0 = *(const float4*)(erow + lane * 4);
        float4 e1 = *(const float4*)(erow + 256 + lane * 4);
        xe0[j].x = __expf(e0.x); xe0[j].y = __expf(e0.y);
        xe0[j].z = __expf(e0.z); xe0[j].w = __expf(e0.w);
        xe1[j].x = __expf(e1.x); xe1[j].y = __expf(e1.y);
        xe1[j].z = __expf(e1.z); xe1[j].w = __expf(e1.w);
    }

    for (int u = wave; u <= U_; u += 4) {
        const float* xdrow = edec + (size_t)(b * U1_ + u) * V_;
        float4 d0 = *(const float4*)(xdrow + lane * 4);
        float4 d1 = *(const float4*)(xdrow + 256 + lane * 4);

        float s[NT_];
        #pragma unroll
        for (int j = 0; j < NT_; ++j) {
            float sA = xe0[j].x * d0.x;
            float sB = xe1[j].x * d1.x;
            sA = fmaf(xe0[j].y, d0.y, sA);  sB = fmaf(xe1[j].y, d1.y, sB);
            sA = fmaf(xe0[j].z, d0.z, sA);  sB = fmaf(xe1[j].z, d1.z, sB);
            sA = fmaf(xe0[j].w, d0.w, sA);  sB = fmaf(xe1[j].w, d1.w, sB);
            s[j] = sA + sB;
        }

        #pragma unroll
        for (int off = 32; off > 0; off >>= 1) {
            #pragma unroll
            for (int j = 0; j < NT_; ++j)
                s[j] += __shfl_xor(s[j], off, 64);
        }

        if (lane == 0) {
            const float* dr = dec + (size_t)(b * U1_ + u) * V_;
            const float d_blank = dr[0];
            int   tgt = 0;
            float d_tgt = 0.0f;
            if (u < U_) { tgt = targets[b * U_ + u]; d_tgt = dr[tgt]; }
            #pragma unroll
            for (int j = 0; j < NT_; ++j) {
                const int t  = t0 + j;
                const int dg = t + u;
                const float lse2 = log2f(s[j]);
                const float* er = enc + (size_t)(b * T_ + t) * V_;
                BLD[((size_t)b * NDIAGP_ + dg) * U1_ + u] =
                    (er[0] + d_blank) * LOG2E_ - lse2;
                if (u < U_)
                    EMD[((size_t)b * NDIAGP_ + dg) * U_ + u] =
                        (er[tgt] + d_tgt) * LOG2E_ - lse2;
            }
        }
    }
}

// ---------------------------------------------------------------------------
// Kernel 2: alpha wavefront recursion (log2 domain). Lane l holds u = l+1;
// the u=0 column is a pure blank-add chain kept as wave-uniform scalar c0.
// One lae2 chain per diagonal. Waves 1-3 stage chunks; wave 0 computes.
// ---------------------------------------------------------------------------
__device__ __forceinline__ float wshr1(float x) {
    // DPP wave_shr:1 (0x138): lane i <- lane i-1, lane 0 <- 0 (bound_ctrl)
    return __int_as_float(__builtin_amdgcn_update_dpp(
        0, __float_as_int(x), 0x138, 0xf, 0xf, true));
}

#define STAGE(c_) do {                                                          \
    if (wave > 0) {                                                             \
        const float* gbl = BLb + (size_t)(c_) * CH_ * U1_;                      \
        const float* gem = EMb + (size_t)(c_) * CH_ * U_;                       \
        float* lbl_ = sBL[(c_) & 1];                                            \
        float* lem_ = sEM[(c_) & 1];                                            \
        for (int i = wave - 1; i < 17; i += 3)                                  \
            __builtin_amdgcn_global_load_lds(                                   \
                (const __attribute__((address_space(1))) void*)(gbl + i * 256 + lane * 4), \
                (__attribute__((address_space(3))) void*)(lbl_ + i * 256), 16, 0, 0);      \
        for (int i = wave - 1; i < 16; i += 3)                                  \
            __builtin_amdgcn_global_load_lds(                                   \
                (const __attribute__((address_space(1))) void*)(gem + i * 256 + lane * 4), \
                (__attribute__((address_space(3))) void*)(lem_ + i * 256), 16, 0, 0);      \
    }                                                                           \
} while (0)

// relative row sj = (d-1) - d0  (recursion at diag d reads diag d-1)
// PB: blank[t-1][u] = BL row sj, col lane+1 ; PE: emit[t][u-1] = EM row sj, col lane
// PC: blank[d-1][0] = BL row sj, col 0 (uniform broadcast, feeds c0 chain)
#define LOADL(PB, PE, PC, g_) do {                                              \
    _Pragma("unroll")                                                           \
    for (int j = 0; j < 8; ++j) {                                               \
        const int sj = 8 * (g_) + j;                                            \
        PB[j] = lbl[sj * U1_ + lane + 1];                                       \
        PE[j] = lem[sj * U_ + lane];                                            \
        PC[j] = lbl[sj * U1_];                                                  \
    }                                                                           \
} while (0)

#define COMPL(PB, PE, PC, g_, P_) do {                                          \
    _Pragma("unroll")                                                           \
    for (int j = 0; j < 8; ++j) {                                               \
        const int sj = 8 * (g_) + j;                                            \
        const int d  = d0 + sj + 1;                                             \
        float al = wshr1(a);                                                    \
        if (lane == 0) al = c0;                                                 \
        float x = a + PB[j];                                                    \
        if (P_) x = (lane == sj) ? NEG_ : x;   /* t==0: no blank path */        \
        float y  = al + PE[j];                                                  \
        float m  = fmaxf(x, y);                                                 \
        float na = m + LOG2(1.0f + EXP2(-fabsf(x - y)));                        \
        const int t = d - 1 - lane;                                             \
        a = ((unsigned)t < (unsigned)T_) ? na : a;                              \
        if (d == dstar && lane == tl - 1)      /* uniform d-check, rare */      \
            atomicAdd(out, -(a + fblank) * (LN2_ / B_));                        \
        if (tl == 0 && d == il && lane == 0)   /* tl==0: answer is c0 chain */  \
            atomicAdd(out, -(c0 + fblank) * (LN2_ / B_));                       \
        c0 += PC[j];                           /* col0: blank-only add chain */ \
    }                                                                           \
} while (0)

#define CHUNK_BODY(c_, P_) do {                                                 \
    const float* lbl = sBL[(c_) & 1];                                           \
    const float* lem = sEM[(c_) & 1];                                           \
    const int d0 = CH_ * (c_);                                                  \
    float pbA[8], peA[8], pcA[8];                                               \
    float pbB[8], peB[8], pcB[8];                                               \
    LOADL(pbA, peA, pcA, 0);                                                    \
    for (int g = 0; g < 8; g += 2) {                                            \
        LOADL(pbB, peB, pcB, g + 1);                                            \
        COMPL(pbA, peA, pcA, g, P_);                                            \
        if (g + 2 < 8) LOADL(pbA, peA, pcA, g + 2);                             \
        COMPL(pbB, peB, pcB, g + 1, P_);                                        \
    }                                                                           \
} while (0)

__global__ __launch_bounds__(256) void k_alpha(
    const float* __restrict__ BLD, const float* __restrict__ EMD,
    const int* __restrict__ il_, const int* __restrict__ tl_,
    float* __restrict__ out)
{
    __shared__ __align__(16) float sBL[2][LBBL_];
    __shared__ __align__(16) float sEM[2][LBEM_];

    const int b    = blockIdx.x;
    const int wave = threadIdx.x >> 6;
    const int lane = threadIdx.x & 63;
    const int il   = il_[b];
    const int tl   = tl_[b];
    const int dstar = il - 1 + tl;
    const float* BLb = BLD + (size_t)b * NDIAGP_ * U1_;
    const float* EMb = EMD + (size_t)b * NDIAGP_ * U_;
    const float fblank = BLb[(size_t)dstar * U1_ + tl];

    float a  = 0.0f;   // alpha (log2) for u = lane+1
    float c0 = 0.0f;   // alpha (log2) for u = 0 at row t = d-1 (wave-uniform)

    STAGE(0);
    __syncthreads();

    // chunk 0 peeled: carries the t==0 boundary patch
    STAGE(1);
    if (wave == 0) { CHUNK_BODY(0, 1); }
    __syncthreads();

    for (int c = 1; c < NCH_; ++c) {
        if (c + 1 < NCH_) STAGE(c + 1);
        if (wave == 0) { CHUNK_BODY(c, 0); }
        __syncthreads();   // publishes chunk c+1, drains staging loads
    }
}

extern "C" void kernel_launch(void* const* d_in, const int* in_sizes, int n_in,
                              void* d_out, int out_size, void* d_ws, size_t ws_size,
                              hipStream_t stream)
{
    const float* enc     = (const float*)d_in[0];
    const float* dec     = (const float*)d_in[1];
    const int*   targets = (const int*)d_in[2];
    const int*   il      = (const int*)d_in[3];
    const int*   tl      = (const int*)d_in[4];
    float*       out     = (float*)d_out;

    float* edec = (float*)d_ws;                           // B*U1*V
    float* BLD  = edec + (size_t)B_ * U1_ * V_;           // B*NDIAGP*U1
    float* EMD  = BLD  + (size_t)B_ * NDIAGP_ * U1_;      // B*NDIAGP*U_

    (void)hipMemsetAsync(d_out, 0, sizeof(float), stream);

    const int n4 = B_ * U1_ * V_ / 4;
    k_exp<<<(n4 + 255) / 256, 256, 0, stream>>>(dec, edec, n4);
    k_logprobs<<<B_ * T_ / NT_, 256, 0, stream>>>(enc, dec, edec, targets, BLD, EMD);
    k_alpha<<<B_, 256, 0, stream>>>(BLD, EMD, il, tl, out);
}